// Round 1
// 556.870 us; speedup vs baseline: 1.0053x; 1.0053x over previous
//
#include <hip/hip_runtime.h>
#include <stdint.h>
#include <stddef.h>

#define M_TOK 8192
#define N_OUT 4096
#define K_IN  4096
#define R_LORA 16
#define BM 128
#define BN 256
#define BK 32

// fused prologue grid split
#define WEFF_BLOCKS ((K_IN / 1024) * (N_OUT / 32))      // 4 * 128 = 512
#define CAST_BLOCKS ((M_TOK * K_IN) / (8 * 256))        // 8 floats/thread -> 16384

typedef __bf16 bf16_t;
typedef __bf16 bf16x4 __attribute__((ext_vector_type(4)));
typedef __bf16 bf16x8 __attribute__((ext_vector_type(8)));
typedef float floatx4 __attribute__((ext_vector_type(4)));

// async global->LDS, 16B per lane. LDS dest must be wave-uniform base; HW adds lane*16.
__device__ inline void async_copy16(const bf16_t* g, bf16_t* l) {
  __builtin_amdgcn_global_load_lds(
      (__attribute__((address_space(1))) void*)(uintptr_t)(const void*)g,
      (__attribute__((address_space(3))) void*)l,
      16, 0, 0);
}

// ---------------- fused prologue ----------------
// One dispatch does BOTH prologue jobs so their memory streams overlap:
//   blocks [0, WEFF_BLOCKS)                : Weff = W + scale*B@A -> bf16 (heavy, launched first)
//   blocks [WEFF_BLOCKS, +CAST_BLOCKS)     : x fp32 -> bf16 cast, 32B/thread read, 16B store
// Ideal combined traffic 301 MB ~= 48us @ 6.3 TB/s; previously these were two
// serialized launches summing to ~238us (560 total - 322 gemm).
__global__ __launch_bounds__(256) void prep_fused(
    const float* __restrict__ x, bf16_t* __restrict__ xb,
    const float* __restrict__ W, const float* __restrict__ lB,
    const float* __restrict__ lA, const float* __restrict__ scale_p,
    bf16_t* __restrict__ wb) {
  const int b = blockIdx.x;
  if (b < WEFF_BLOCKS) {
    // ---- Weff part: block = (K-chunk of 1024) x (32 rows). Thread keeps its
    // 16x4 slice of lora_A in registers; lora_B is a uniform scalar load per row.
    const int kbase = (b & 3) * 1024 + threadIdx.x * 4;  // K_IN/1024 == 4
    const int o0    = (b >> 2) * 32;
    const float scale = *scale_p;

    float4 areg[R_LORA];
#pragma unroll
    for (int r = 0; r < R_LORA; ++r)
      areg[r] = *(const float4*)(lA + (size_t)r * K_IN + kbase);

    for (int oo = 0; oo < 32; ++oo) {
      const int o = o0 + oo;
      float4 w = *(const float4*)(W + (size_t)o * K_IN + kbase);
      float a0 = w.x, a1 = w.y, a2 = w.z, a3 = w.w;
#pragma unroll
      for (int r = 0; r < R_LORA; ++r) {
        float bb = lB[(size_t)o * R_LORA + r] * scale;  // block-uniform -> s_load
        a0 += bb * areg[r].x; a1 += bb * areg[r].y;
        a2 += bb * areg[r].z; a3 += bb * areg[r].w;
      }
      bf16x4 v;
      v[0] = (bf16_t)a0; v[1] = (bf16_t)a1; v[2] = (bf16_t)a2; v[3] = (bf16_t)a3;
      *(bf16x4*)(wb + (size_t)o * K_IN + kbase) = v;
    }
  } else {
    // ---- cast part: 2 float4 loads (32B) + one bf16x8 store (16B) per thread.
    const size_t t = (size_t)(b - WEFF_BLOCKS) * 256 + threadIdx.x;
    const float4* xp = (const float4*)x + t * 2;
    float4 a0 = xp[0];
    float4 a1 = xp[1];
    bf16x8 v;
    v[0] = (bf16_t)a0.x; v[1] = (bf16_t)a0.y; v[2] = (bf16_t)a0.z; v[3] = (bf16_t)a0.w;
    v[4] = (bf16_t)a1.x; v[5] = (bf16_t)a1.y; v[6] = (bf16_t)a1.z; v[7] = (bf16_t)a1.w;
    *(bf16x8*)(xb + t * 8) = v;
  }
}

// ---------------- pass 2: C = A @ Bw^T + bias (UNCHANGED from 550us version) ----------------
// BM=128 x BN=256 block tile, 4 waves, each 64x128 (4x8 of 16x16x32 bf16 MFMA).
// k-chunk rotation swizzle (conflicts 3.35e7 -> 0): slot s -> row s>>2,
// chunk ((s&3)-(s>>3))&3; fragment chunk offset ((quad+(lr>>1))&3)*8.
// Double-buffered LDS, one barrier per K-iter; stage(k+1) issued after the
// barrier so the barrier's vmcnt(0) drain lands on a load that had a full
// compute phase in flight.
__global__ __launch_bounds__(256, 2) void gemm_bt(const bf16_t* __restrict__ A,
                                                  const bf16_t* __restrict__ Bw,
                                                  const float* __restrict__ bias,
                                                  float* __restrict__ C) {
  __shared__ bf16_t sA[2 * BM * BK];  // 16 KB (two 8 KB buffers)
  __shared__ bf16_t sB[2 * BN * BK];  // 32 KB (two 16 KB buffers)

  const int tid  = threadIdx.x;
  const int wave = tid >> 6;
  const int lane = tid & 63;
  const int lr   = lane & 15;
  const int quad = lane >> 4;
  const int bm = blockIdx.y * BM;
  const int bn = blockIdx.x * BN;
  const int wm = (wave >> 1) * 64;   // wave's 64x128 sub-tile
  const int wn = (wave & 1) * 128;

  // ---- staging pointers ----
  const bf16_t* gA[2];
  const bf16_t* gB[4];
  bf16_t* lA0[2];
  bf16_t* lB0[4];
#pragma unroll
  for (int i = 0; i < 2; ++i) {
    int s = i * 256 + wave * 64 + lane;
    int row = s >> 2;
    int q = ((s & 3) - (s >> 3)) & 3;  // swizzled k-chunk this lane fetches
    gA[i] = A + (size_t)(bm + row) * K_IN + q * 8;
    lA0[i] = sA + (size_t)(i * 256 + wave * 64) * 8;  // wave-uniform base, buffer 0
  }
#pragma unroll
  for (int i = 0; i < 4; ++i) {
    int s = i * 256 + wave * 64 + lane;
    int row = s >> 2;
    int q = ((s & 3) - (s >> 3)) & 3;
    gB[i] = Bw + (size_t)(bn + row) * K_IN + q * 8;
    lB0[i] = sB + (size_t)(i * 256 + wave * 64) * 8;
  }

  // ---- fragment read pointers (buffer 0; buffer 1 = +BM*BK / +BN*BK elems) ----
  const int cofs = ((quad + (lr >> 1)) & 3) * 8;
  const bf16_t* fA[4];
  const bf16_t* fB[8];
#pragma unroll
  for (int i = 0; i < 4; ++i) fA[i] = sA + (wm + i * 16 + lr) * 32 + cofs;
#pragma unroll
  for (int j = 0; j < 8; ++j) fB[j] = sB + (wn + j * 16 + lr) * 32 + cofs;

  floatx4 acc[4][8];
#pragma unroll
  for (int i = 0; i < 4; ++i)
#pragma unroll
    for (int j = 0; j < 8; ++j) acc[i][j] = {0.f, 0.f, 0.f, 0.f};

#define STAGE(buf_ofsA, buf_ofsB)                                   \
  do {                                                              \
    async_copy16(gA[0], lA0[0] + (buf_ofsA));                       \
    async_copy16(gA[1], lA0[1] + (buf_ofsA));                       \
    async_copy16(gB[0], lB0[0] + (buf_ofsB));                       \
    async_copy16(gB[1], lB0[1] + (buf_ofsB));                       \
    async_copy16(gB[2], lB0[2] + (buf_ofsB));                       \
    async_copy16(gB[3], lB0[3] + (buf_ofsB));                       \
    gA[0] += BK; gA[1] += BK;                                       \
    gB[0] += BK; gB[1] += BK; gB[2] += BK; gB[3] += BK;             \
  } while (0)

#define COMPUTE(buf_ofsA, buf_ofsB)                                                   \
  do {                                                                                \
    bf16x8 a[4], b[8];                                                                \
    _Pragma("unroll") for (int i = 0; i < 4; ++i)                                     \
        a[i] = *(const bf16x8*)(fA[i] + (buf_ofsA));                                  \
    _Pragma("unroll") for (int j = 0; j < 8; ++j)                                     \
        b[j] = *(const bf16x8*)(fB[j] + (buf_ofsB));                                  \
    _Pragma("unroll") for (int i = 0; i < 4; ++i)                                     \
        _Pragma("unroll") for (int j = 0; j < 8; ++j)                                 \
            acc[i][j] = __builtin_amdgcn_mfma_f32_16x16x32_bf16(a[i], b[j],           \
                                                                acc[i][j], 0, 0, 0); \
  } while (0)

  STAGE(0, 0);  // k = 0 into buffer 0
  for (int it = 0; it < K_IN / BK; it += 2) {
    __syncthreads();              // drains stage(it) [flew during compute(it-1)]
    STAGE(BM * BK, BN * BK);      // k = it+1 into buffer 1
    COMPUTE(0, 0);                // compute k = it from buffer 0
    __syncthreads();              // drains stage(it+1) [flew during compute(it)]
    if (it + 2 < K_IN / BK) STAGE(0, 0);  // k = it+2 into buffer 0
    COMPUTE(BM * BK, BN * BK);    // compute k = it+1 from buffer 1
  }
#undef STAGE
#undef COMPUTE

  // Epilogue: row = quad*4 + reg (A side), col = lr (B side)
#pragma unroll
  for (int j = 0; j < 8; ++j) {
    int col = bn + wn + j * 16 + lr;
    float bb = bias[col];
#pragma unroll
    for (int i = 0; i < 4; ++i) {
      int row0 = bm + wm + i * 16 + quad * 4;
      floatx4 v = acc[i][j];
#pragma unroll
      for (int r = 0; r < 4; ++r)
        C[(size_t)(row0 + r) * N_OUT + col] = v[r] + bb;
    }
  }
}

// ---------------- fallback (workspace too small): fp32 path ----------------
__global__ __launch_bounds__(256) void lora_xa(const float* __restrict__ x,
                                               const float* __restrict__ lA,
                                               const float* __restrict__ scale_p,
                                               float* __restrict__ t) {
  int m = blockIdx.x;
  int r = threadIdx.x & 15;
  int kcn = threadIdx.x >> 4;
  float acc = 0.f;
  const float* xr = x + (size_t)m * K_IN + kcn * 256;
  const float* ar = lA + (size_t)r * K_IN + kcn * 256;
  for (int k = 0; k < 256; k += 4) {
    float4 xv = *(const float4*)(xr + k);
    float4 av = *(const float4*)(ar + k);
    acc += xv.x * av.x + xv.y * av.y + xv.z * av.z + xv.w * av.w;
  }
  __shared__ float s[256];
  s[threadIdx.x] = acc;
  __syncthreads();
  if (threadIdx.x < 16) {
    float v = 0.f;
    for (int i = 0; i < 16; ++i) v += s[threadIdx.x + i * 16];
    t[(size_t)m * 16 + threadIdx.x] = v * (*scale_p);
  }
}

__global__ __launch_bounds__(256) void gemm_f32_fb(const float* __restrict__ X,
                                                   const float* __restrict__ W,
                                                   const float* __restrict__ bias,
                                                   const float* __restrict__ t,
                                                   const float* __restrict__ lB,
                                                   float* __restrict__ C) {
  __shared__ float sX[64][17];
  __shared__ float sW[64][17];
  int tid = threadIdx.x;
  int tx = tid & 15, ty = tid >> 4;
  int m0 = blockIdx.y * 64, n0 = blockIdx.x * 64;
  int lrow = tid >> 2, lcol = (tid & 3) * 4;
  float acc[4][4] = {};
  for (int k0 = 0; k0 < K_IN; k0 += 16) {
    __syncthreads();
    float4 xv = *(const float4*)(X + (size_t)(m0 + lrow) * K_IN + k0 + lcol);
    float4 wv = *(const float4*)(W + (size_t)(n0 + lrow) * K_IN + k0 + lcol);
    sX[lrow][lcol + 0] = xv.x; sX[lrow][lcol + 1] = xv.y;
    sX[lrow][lcol + 2] = xv.z; sX[lrow][lcol + 3] = xv.w;
    sW[lrow][lcol + 0] = wv.x; sW[lrow][lcol + 1] = wv.y;
    sW[lrow][lcol + 2] = wv.z; sW[lrow][lcol + 3] = wv.w;
    __syncthreads();
#pragma unroll
    for (int kk = 0; kk < 16; ++kk) {
      float xr[4], wr[4];
#pragma unroll
      for (int i = 0; i < 4; ++i) { xr[i] = sX[ty * 4 + i][kk]; wr[i] = sW[tx * 4 + i][kk]; }
#pragma unroll
      for (int i = 0; i < 4; ++i)
#pragma unroll
        for (int j = 0; j < 4; ++j) acc[i][j] += xr[i] * wr[j];
    }
  }
  for (int j = 0; j < 4; ++j) {
    int n = n0 + tx * 4 + j;
    float bb = bias[n];
    for (int i = 0; i < 4; ++i) {
      int m = m0 + ty * 4 + i;
      float l = 0.f;
      for (int r = 0; r < R_LORA; ++r) l += t[(size_t)m * 16 + r] * lB[(size_t)n * 16 + r];
      C[(size_t)m * N_OUT + n] = acc[i][j] + bb + l;
    }
  }
}

extern "C" void kernel_launch(void* const* d_in, const int* in_sizes, int n_in,
                              void* d_out, int out_size, void* d_ws, size_t ws_size,
                              hipStream_t stream) {
  const float* x     = (const float*)d_in[0];
  const float* W     = (const float*)d_in[1];
  const float* bias  = (const float*)d_in[2];
  const float* lB    = (const float*)d_in[3];
  const float* lA    = (const float*)d_in[4];
  const float* scale = (const float*)d_in[5];
  float* out = (float*)d_out;

  const size_t x_bytes = (size_t)M_TOK * K_IN * sizeof(bf16_t);  // 64 MB
  const size_t w_bytes = (size_t)N_OUT * K_IN * sizeof(bf16_t);  // 32 MB

  if (ws_size >= x_bytes + w_bytes) {
    bf16_t* xb = (bf16_t*)d_ws;
    bf16_t* wb = (bf16_t*)((char*)d_ws + x_bytes);
    prep_fused<<<WEFF_BLOCKS + CAST_BLOCKS, 256, 0, stream>>>(x, xb, W, lB, lA, scale, wb);
    gemm_bt<<<dim3(N_OUT / BN, M_TOK / BM), 256, 0, stream>>>(xb, wb, bias, out);
  } else {
    float* t = (float*)d_ws;
    lora_xa<<<M_TOK, 256, 0, stream>>>(x, lA, scale, t);
    gemm_f32_fb<<<dim3(N_OUT / 64, M_TOK / 64), 256, 0, stream>>>(x, W, bias, t, lB, out);
  }
}